// Round 12
// baseline (371.821 us; speedup 1.0000x reference)
//
#include <hip/hip_runtime.h>
#include <hip/hip_bf16.h>
#include <math.h>

#define NN 100000   // nodes
#define EE 300000   // edges per type
#define TT 3        // edge types
#define LL 2        // layers
#define HH 128      // hidden
#define FF 5        // node feat
#define TE 64       // type embed
#define NT 200      // num ast types
#define BB 64       // graphs
#define NC 16       // pooling chunks per graph
#define CSRCAP 512  // per-type per-block LDS index cap (mean ~192)
#define WLSZ 131072 // per-layer fragment-packed weight size (shorts)
#define KIN 96      // padded K for input projection (69 -> 96)
#define IALD 104    // input-proj LDS row stride (shorts)

typedef short bf16x8 __attribute__((ext_vector_type(8)));
typedef float f32x4  __attribute__((ext_vector_type(4)));

__device__ __forceinline__ float bf2f(unsigned short u) {
    union { unsigned i; float f; } v; v.i = ((unsigned)u) << 16; return v.f;
}
__device__ __forceinline__ float bflo(unsigned u) {
    union { unsigned i; float f; } v; v.i = u << 16; return v.f;
}
__device__ __forceinline__ float bfhi(unsigned u) {
    union { unsigned i; float f; } v; v.i = u & 0xFFFF0000u; return v.f;
}
__device__ __forceinline__ unsigned short f2bf(float f) {
    union { float f; unsigned i; } v; v.f = f;
    unsigned b = v.i + (0x7FFFu + ((v.i >> 16) & 1u));   // RNE
    return (unsigned short)(b >> 16);
}
__device__ __forceinline__ unsigned pk2(float a, float b) {
    return (unsigned)f2bf(a) | ((unsigned)f2bf(b) << 16);
}
// split x ~= hi + lo (two bf16); hi+lo reproduces x to ~2^-16 rel
__device__ __forceinline__ void split_bf(float x, unsigned short& hi, unsigned short& lo) {
    hi = f2bf(x);
    lo = f2bf(x - bf2f(hi));
}

// ================================================================ CSR build (validated R2)
__global__ void count_kernel(const int* __restrict__ ei, int* __restrict__ cnt) {
    int i = blockIdx.x * blockDim.x + threadIdx.x;
    if (i >= TT * EE) return;
    int t = i / EE, e = i - t * EE;
    int dst = ei[(t * 2 + 1) * EE + e];
    atomicAdd(&cnt[t * NN + dst], 1);
}

__global__ __launch_bounds__(256) void scan1_kernel(const int* __restrict__ cnt,
                                                    int* __restrict__ offs,
                                                    int* __restrict__ bsums, int M) {
    int tid = threadIdx.x;
    int base = blockIdx.x * 1024 + tid * 4;
    int a0 = 0, a1 = 0, a2 = 0, a3 = 0;
    if (base + 3 < M) { int4 v = *(const int4*)&cnt[base]; a0 = v.x; a1 = v.y; a2 = v.z; a3 = v.w; }
    else {
        if (base + 0 < M) a0 = cnt[base + 0];
        if (base + 1 < M) a1 = cnt[base + 1];
        if (base + 2 < M) a2 = cnt[base + 2];
        if (base + 3 < M) a3 = cnt[base + 3];
    }
    int s = a0 + a1 + a2 + a3;
    int lane = tid & 63, wv = tid >> 6;
    int x = s;
    #pragma unroll
    for (int o = 1; o < 64; o <<= 1) { int y = __shfl_up(x, o); if (lane >= o) x += y; }
    __shared__ int wsum[4];
    if (lane == 63) wsum[wv] = x;
    __syncthreads();
    int add = 0;
    for (int w = 0; w < wv; ++w) add += wsum[w];
    int incl = x + add;
    int e0 = incl - s, e1 = e0 + a0, e2 = e1 + a1, e3 = e2 + a2;
    if (base + 0 < M) offs[base + 0] = e0;
    if (base + 1 < M) offs[base + 1] = e1;
    if (base + 2 < M) offs[base + 2] = e2;
    if (base + 3 < M) offs[base + 3] = e3;
    if (tid == 255) bsums[blockIdx.x] = incl;
}

__global__ __launch_bounds__(512) void scan2_kernel(int* __restrict__ bsums, int NB) {
    int tid = threadIdx.x;
    int s = (tid < NB) ? bsums[tid] : 0;
    int lane = tid & 63, wv = tid >> 6;
    int x = s;
    #pragma unroll
    for (int o = 1; o < 64; o <<= 1) { int y = __shfl_up(x, o); if (lane >= o) x += y; }
    __shared__ int wsum[8];
    if (lane == 63) wsum[wv] = x;
    __syncthreads();
    int add = 0;
    for (int w = 0; w < wv; ++w) add += wsum[w];
    if (tid < NB) bsums[tid] = x + add - s;
}

__global__ void scan3_kernel(int* __restrict__ offs, const int* __restrict__ bsums,
                             int* __restrict__ cursor, int M) {
    int i = blockIdx.x * 256 + threadIdx.x;
    if (i >= M) return;
    int v = offs[i] + bsums[i >> 10];
    offs[i] = v;
    cursor[i] = v;
}

__global__ void fill_kernel(const int* __restrict__ ei, int* __restrict__ cursor,
                            int* __restrict__ csr) {
    int i = blockIdx.x * blockDim.x + threadIdx.x;
    if (i >= TT * EE) return;
    int t = i / EE, e = i - t * EE;
    int src = ei[(t * 2 + 0) * EE + e];
    int dst = ei[(t * 2 + 1) * EE + e];
    int pos = atomicAdd(&cursor[t * NN + dst], 1);
    csr[pos] = src;
}

// ================================================================ weight prep (conv + input-proj merged)
__global__ void wprep_kernel(const float* __restrict__ W_l, const float* __restrict__ W_r,
                             const float* __restrict__ b_l, const float* __restrict__ W_in,
                             unsigned short* __restrict__ Wt16, unsigned short* __restrict__ Wp,
                             float* __restrict__ blsum) {
    int i = blockIdx.x * 256 + threadIdx.x;
    if (i < LL * 4 * HH * HH) {
        int lm = i >> 14;          // l*4 + m
        int ck = i & 16383;
        int col = ck >> 7, k = ck & 127;
        int l = lm >> 2, m = lm & 3;
        float v;
        if (m == 0) {
            v = 0.f;
            for (int t = 0; t < TT; ++t)
                v += W_r[(((size_t)(l * TT + t)) << 14) + k * HH + col];
        } else {
            v = W_l[(((size_t)(l * TT + (m - 1))) << 14) + k * HH + col];
        }
        unsigned short hi, lo;
        split_bf(v, hi, lo);
        int cg = col >> 4, l15 = col & 15;
        int ks = k >> 5, lh = (k >> 3) & 3, j = k & 7;
        int lane = lh * 16 + l15;
        size_t base = (size_t)l * WLSZ;
        int Phi = (m * 2 + 0) * 4 + ks;
        int Plo = Phi + 4;
        Wt16[base + (size_t)Phi * 4096 + cg * 512 + lane * 8 + j] = hi;
        Wt16[base + (size_t)Plo * 4096 + cg * 512 + lane * 8 + j] = lo;
    }
    if (i < KIN * HH) {
        int col = i & 127, k = i >> 7;
        float v = (k < TE + FF) ? W_in[k * HH + col] : 0.f;
        unsigned short hi, lo;
        split_bf(v, hi, lo);
        int cg = col >> 4, l15 = col & 15;
        int ks = k >> 5, lh = (k >> 3) & 3, j = k & 7;
        int lane = lh * 16 + l15;
        Wp[(size_t)ks * 4096 + cg * 512 + lane * 8 + j]       = hi;
        Wp[(size_t)(4 + ks) * 4096 + cg * 512 + lane * 8 + j] = lo;
    }
    if (i < LL * HH) {
        int l = i >> 7, j = i & 127;
        float s = 0.f;
        for (int t = 0; t < TT; ++t) s += b_l[(l * TT + t) * HH + j];
        blsum[i] = s;
    }
}

// ================================================================ input projection (split-bf16 MFMA, validated R11)
__global__ __launch_bounds__(512) void input_proj_kernel(
    const float* __restrict__ x, const int* __restrict__ ast,
    const float* __restrict__ emb, const unsigned short* __restrict__ Wp,
    const float* __restrict__ b_in, unsigned short* __restrict__ h16)
{
    __shared__ unsigned short Ahi[64 * IALD];   // 13.3 KB
    __shared__ unsigned short Alo[64 * IALD];   // 13.3 KB

    int tid = threadIdx.x;
    int row0 = blockIdx.x * 64;
    int w = tid >> 6, l = tid & 63;
    int l15 = l & 15, koff = (l >> 4) * 8;

    // ---- stage A-tile: 8 threads x 12 cols per row (96 cols)
    {
        int r = tid >> 3, sub = tid & 7;
        int gr = row0 + r;
        float v[12];
        #pragma unroll
        for (int j = 0; j < 12; ++j) v[j] = 0.f;
        if (gr < NN) {
            int a = ast[gr];
            #pragma unroll
            for (int j = 0; j < 12; ++j) {
                int k = sub * 12 + j;
                if (k < TE) v[j] = emb[a * TE + k];
                else if (k < TE + FF) v[j] = x[gr * FF + (k - TE)];
            }
        }
        unsigned short hs[12], ls[12];
        #pragma unroll
        for (int j = 0; j < 12; ++j) split_bf(v[j], hs[j], ls[j]);
        unsigned uh[6], ul[6];
        #pragma unroll
        for (int q = 0; q < 6; ++q) {
            uh[q] = (unsigned)hs[2 * q] | ((unsigned)hs[2 * q + 1] << 16);
            ul[q] = (unsigned)ls[2 * q] | ((unsigned)ls[2 * q + 1] << 16);
        }
        int base = r * IALD + sub * 12;
        uint2 h0; h0.x = uh[0]; h0.y = uh[1];
        uint2 h1; h1.x = uh[2]; h1.y = uh[3];
        uint2 h2; h2.x = uh[4]; h2.y = uh[5];
        uint2 l0; l0.x = ul[0]; l0.y = ul[1];
        uint2 l1; l1.x = ul[2]; l1.y = ul[3];
        uint2 l2; l2.x = ul[4]; l2.y = ul[5];
        *(uint2*)&Ahi[base + 0] = h0;
        *(uint2*)&Ahi[base + 4] = h1;
        *(uint2*)&Ahi[base + 8] = h2;
        *(uint2*)&Alo[base + 0] = l0;
        *(uint2*)&Alo[base + 4] = l1;
        *(uint2*)&Alo[base + 8] = l2;
    }
    __syncthreads();

    // ---- MFMA: 3 k-steps, W fragments direct from L2-hot pack
    f32x4 acc[4] = {};
    #pragma unroll
    for (int ks = 0; ks < 3; ++ks) {
        bf16x8 wh = *(const bf16x8*)&Wp[(size_t)ks * 4096 + w * 512 + l * 8];
        bf16x8 wl = *(const bf16x8*)&Wp[(size_t)(4 + ks) * 4096 + w * 512 + l * 8];
        int k0 = ks * 32 + koff;
        #pragma unroll
        for (int rt = 0; rt < 4; ++rt) {
            bf16x8 ah = *(const bf16x8*)&Ahi[(rt * 16 + l15) * IALD + k0];
            bf16x8 al = *(const bf16x8*)&Alo[(rt * 16 + l15) * IALD + k0];
            acc[rt] = __builtin_amdgcn_mfma_f32_16x16x32_bf16(ah, wh, acc[rt], 0, 0, 0);
            acc[rt] = __builtin_amdgcn_mfma_f32_16x16x32_bf16(al, wh, acc[rt], 0, 0, 0);
            acc[rt] = __builtin_amdgcn_mfma_f32_16x16x32_bf16(ah, wl, acc[rt], 0, 0, 0);
        }
    }

    // ---- bias + bf16 store (m89 C/D layout, validated epilogue pattern)
    {
        int col = w * 16 + l15;
        float bv = b_in[col];
        int rbase = row0 + (l >> 4) * 4;
        #pragma unroll
        for (int rt = 0; rt < 4; ++rt) {
            #pragma unroll
            for (int i = 0; i < 4; ++i) {
                int grr = rbase + rt * 16 + i;
                if (grr < NN) h16[(size_t)grr * HH + col] = f2bf(acc[rt][i] + bv);
            }
        }
    }
}

// ================================================================ conv layer (bf16 MFMA, batched gather)
// R12: gather loop unrolled 4 edges per batch -> 4x fewer vmcnt latency
// exposures. Accumulation order per dim is IDENTICAL to R11 (bitwise-same).
#define ALD 136   // padded LDS stride (shorts): 272 B -> 2-way bank aliasing (free)

__global__ __launch_bounds__(512) void conv_kernel(
    const unsigned short* __restrict__ h16,      // [N][128] bf16 (dense A + gather)
    const unsigned short* __restrict__ Wt_l,     // fragment-packed, per-layer base
    const float* __restrict__ blsum_l,
    const int* __restrict__ offs, const int* __restrict__ cnt, const int* __restrict__ csr,
    unsigned short* __restrict__ ob16)
{
    __shared__ unsigned short Ahi[64 * ALD];     // 17.4 KB
    __shared__ int csr_lds[TT][CSRCAP];          // 6 KB
    __shared__ int base_lds[TT], len_lds[TT], flag_lds[TT];

    int tid = threadIdx.x;
    int row0 = blockIdx.x * 64;
    int nrow = min(64, NN - row0);
    int w = tid >> 6, l = tid & 63;
    int l15 = l & 15, koff = (l >> 4) * 8;

    // ---- stage CSR ranges (rows consecutive -> contiguous csr slice per type)
    if (tid < TT) {
        int t = tid;
        int last = row0 + nrow - 1;
        int b = offs[t * NN + row0];
        int e = offs[t * NN + last] + cnt[t * NN + last];
        base_lds[t] = b;
        len_lds[t] = e - b;
        flag_lds[t] = (e - b) <= CSRCAP;
    }
    __syncthreads();
    #pragma unroll
    for (int t = 0; t < TT; ++t) {
        if (flag_lds[t]) {
            int b = base_lds[t], len = len_lds[t];
            for (int i = tid; i < len; i += 512) csr_lds[t][i] = csr[b + i];
        }
    }
    __syncthreads();

    int r = tid >> 3, sub = tid & 7;
    int gr = row0 + r;

    f32x4 acc[4] = {};

    #pragma unroll
    for (int m = 0; m < 4; ++m) {
        // ---- stage A-tile (single bf16 plane)
        if (m == 0) {
            #pragma unroll
            for (int s2 = 0; s2 < 2; ++s2) {
                int c16 = s2 * 512 + tid;
                int rr = c16 >> 4, k0 = (c16 & 15) * 8;
                int grr = row0 + rr;
                uint4 hv = {0u, 0u, 0u, 0u};
                if (grr < NN) hv = *(const uint4*)&h16[(size_t)grr * 128 + k0];
                *(uint4*)&Ahi[rr * ALD + k0] = hv;
            }
        } else {
            int t = m - 1;   // static under #pragma unroll
            // ---- gather mean_t: 4-edge batched loads (accum order == R11)
            float ms[16];
            #pragma unroll
            for (int j = 0; j < 16; ++j) ms[j] = 0.f;
            float inv = 0.f;
            if (gr < NN) {
                int o = offs[t * NN + gr];
                int c = cnt[t * NN + gr];
                inv = (c > 0) ? 1.0f / (float)c : 0.0f;
                bool inl = flag_lds[t] != 0;
                int rel = o - base_lds[t];
                const unsigned* h16u = (const unsigned*)h16;
                int j = 0;
                for (; j + 4 <= c; j += 4) {
                    int s0 = inl ? csr_lds[t][rel + j + 0] : csr[o + j + 0];
                    int s1 = inl ? csr_lds[t][rel + j + 1] : csr[o + j + 1];
                    int s2 = inl ? csr_lds[t][rel + j + 2] : csr[o + j + 2];
                    int s3 = inl ? csr_lds[t][rel + j + 3] : csr[o + j + 3];
                    const uint4* p0 = (const uint4*)&h16u[(size_t)s0 * 64 + sub * 8];
                    const uint4* p1 = (const uint4*)&h16u[(size_t)s1 * 64 + sub * 8];
                    const uint4* p2 = (const uint4*)&h16u[(size_t)s2 * 64 + sub * 8];
                    const uint4* p3 = (const uint4*)&h16u[(size_t)s3 * 64 + sub * 8];
                    uint4 a0 = p0[0], b0 = p0[1];
                    uint4 a1 = p1[0], b1 = p1[1];
                    uint4 a2 = p2[0], b2 = p2[1];
                    uint4 a3 = p3[0], b3 = p3[1];
                    // edge j (same order as scalar loop)
                    ms[0]+=bflo(a0.x); ms[1]+=bfhi(a0.x); ms[2]+=bflo(a0.y); ms[3]+=bfhi(a0.y);
                    ms[4]+=bflo(a0.z); ms[5]+=bfhi(a0.z); ms[6]+=bflo(a0.w); ms[7]+=bfhi(a0.w);
                    ms[8]+=bflo(b0.x); ms[9]+=bfhi(b0.x); ms[10]+=bflo(b0.y); ms[11]+=bfhi(b0.y);
                    ms[12]+=bflo(b0.z); ms[13]+=bfhi(b0.z); ms[14]+=bflo(b0.w); ms[15]+=bfhi(b0.w);
                    // edge j+1
                    ms[0]+=bflo(a1.x); ms[1]+=bfhi(a1.x); ms[2]+=bflo(a1.y); ms[3]+=bfhi(a1.y);
                    ms[4]+=bflo(a1.z); ms[5]+=bfhi(a1.z); ms[6]+=bflo(a1.w); ms[7]+=bfhi(a1.w);
                    ms[8]+=bflo(b1.x); ms[9]+=bfhi(b1.x); ms[10]+=bflo(b1.y); ms[11]+=bfhi(b1.y);
                    ms[12]+=bflo(b1.z); ms[13]+=bfhi(b1.z); ms[14]+=bflo(b1.w); ms[15]+=bfhi(b1.w);
                    // edge j+2
                    ms[0]+=bflo(a2.x); ms[1]+=bfhi(a2.x); ms[2]+=bflo(a2.y); ms[3]+=bfhi(a2.y);
                    ms[4]+=bflo(a2.z); ms[5]+=bfhi(a2.z); ms[6]+=bflo(a2.w); ms[7]+=bfhi(a2.w);
                    ms[8]+=bflo(b2.x); ms[9]+=bfhi(b2.x); ms[10]+=bflo(b2.y); ms[11]+=bfhi(b2.y);
                    ms[12]+=bflo(b2.z); ms[13]+=bfhi(b2.z); ms[14]+=bflo(b2.w); ms[15]+=bfhi(b2.w);
                    // edge j+3
                    ms[0]+=bflo(a3.x); ms[1]+=bfhi(a3.x); ms[2]+=bflo(a3.y); ms[3]+=bfhi(a3.y);
                    ms[4]+=bflo(a3.z); ms[5]+=bfhi(a3.z); ms[6]+=bflo(a3.w); ms[7]+=bfhi(a3.w);
                    ms[8]+=bflo(b3.x); ms[9]+=bfhi(b3.x); ms[10]+=bflo(b3.y); ms[11]+=bfhi(b3.y);
                    ms[12]+=bflo(b3.z); ms[13]+=bfhi(b3.z); ms[14]+=bflo(b3.w); ms[15]+=bfhi(b3.w);
                }
                for (; j < c; ++j) {
                    int src = inl ? csr_lds[t][rel + j] : csr[o + j];
                    const uint4* hp = (const uint4*)&h16u[(size_t)src * 64 + sub * 8];
                    uint4 v0 = hp[0], v1 = hp[1];
                    ms[0]  += bflo(v0.x); ms[1]  += bfhi(v0.x);
                    ms[2]  += bflo(v0.y); ms[3]  += bfhi(v0.y);
                    ms[4]  += bflo(v0.z); ms[5]  += bfhi(v0.z);
                    ms[6]  += bflo(v0.w); ms[7]  += bfhi(v0.w);
                    ms[8]  += bflo(v1.x); ms[9]  += bfhi(v1.x);
                    ms[10] += bflo(v1.y); ms[11] += bfhi(v1.y);
                    ms[12] += bflo(v1.z); ms[13] += bfhi(v1.z);
                    ms[14] += bflo(v1.w); ms[15] += bfhi(v1.w);
                }
            }
            uint4 hv0, hv1;
            hv0.x = pk2(ms[0] * inv,  ms[1] * inv);
            hv0.y = pk2(ms[2] * inv,  ms[3] * inv);
            hv0.z = pk2(ms[4] * inv,  ms[5] * inv);
            hv0.w = pk2(ms[6] * inv,  ms[7] * inv);
            hv1.x = pk2(ms[8] * inv,  ms[9] * inv);
            hv1.y = pk2(ms[10] * inv, ms[11] * inv);
            hv1.z = pk2(ms[12] * inv, ms[13] * inv);
            hv1.w = pk2(ms[14] * inv, ms[15] * inv);
            *(uint4*)&Ahi[r * ALD + sub * 16]     = hv0;
            *(uint4*)&Ahi[r * ALD + sub * 16 + 8] = hv1;
        }
        __syncthreads();
        // ---- MFMA: A single-plane x W split (wh + wl), W direct from L2-hot pack
        #pragma unroll
        for (int ks = 0; ks < 4; ++ks) {
            bf16x8 wh = *(const bf16x8*)&Wt_l[(size_t)(8 * m + ks) * 4096 + w * 512 + l * 8];
            bf16x8 wl = *(const bf16x8*)&Wt_l[(size_t)(8 * m + 4 + ks) * 4096 + w * 512 + l * 8];
            int k0 = ks * 32 + koff;
            #pragma unroll
            for (int rt = 0; rt < 4; ++rt) {
                bf16x8 ah = *(const bf16x8*)&Ahi[(rt * 16 + l15) * ALD + k0];
                acc[rt] = __builtin_amdgcn_mfma_f32_16x16x32_bf16(ah, wh, acc[rt], 0, 0, 0);
                acc[rt] = __builtin_amdgcn_mfma_f32_16x16x32_bf16(ah, wl, acc[rt], 0, 0, 0);
            }
        }
        __syncthreads();   // before next m overwrites A
    }

    // ---- bias + bf16 global store (m89 C/D layout)
    {
        int col = w * 16 + l15;
        float bv = blsum_l[col];
        int rbase = row0 + (l >> 4) * 4;
        #pragma unroll
        for (int rt = 0; rt < 4; ++rt) {
            #pragma unroll
            for (int i = 0; i < 4; ++i) {
                int grr = rbase + rt * 16 + i;
                if (grr < NN) ob16[(size_t)grr * HH + col] = f2bf(acc[rt][i] + bv);
            }
        }
    }
}

// ================================================================ layernorm (bf16 in/out, validated R10)
__global__ void layernorm_kernel(const unsigned* __restrict__ in16u,
                                 const float* __restrict__ gamma,
                                 const float* __restrict__ beta,
                                 unsigned* __restrict__ out16u, int rows) {
    int lane = threadIdx.x & 63;
    int row = blockIdx.x * 4 + (threadIdx.x >> 6);
    if (row >= rows) return;
    unsigned u = in16u[(size_t)row * 64 + lane];
    float vx = bflo(u), vy = bfhi(u);
    float s = vx + vy, sq = vx * vx + vy * vy;
    #pragma unroll
    for (int o = 32; o; o >>= 1) { s += __shfl_xor(s, o); sq += __shfl_xor(sq, o); }
    float mu = s * (1.0f / HH);
    float var = sq * (1.0f / HH) - mu * mu;
    float r = rsqrtf(var + 1e-5f);
    float2 gj = *reinterpret_cast<const float2*>(&gamma[lane * 2]);
    float2 bj = *reinterpret_cast<const float2*>(&beta[lane * 2]);
    float ox = (vx - mu) * r * gj.x + bj.x;
    float oy = (vy - mu) * r * gj.y + bj.y;
    out16u[(size_t)row * 64 + lane] = pk2(ox, oy);
}

// ================================================================ two-stage pooling (validated R10)
__global__ void pool1_kernel(const unsigned short* __restrict__ h16,
                             const int* __restrict__ batch,
                             float* __restrict__ psum, float* __restrict__ pmax) {
    int g = blockIdx.x >> 4, c = blockIdx.x & (NC - 1);
    int start, end;
    {
        int lo = 0, hi = NN;
        while (lo < hi) { int mid = (lo + hi) >> 1; if (batch[mid] < g) lo = mid + 1; else hi = mid; }
        start = lo;
        hi = NN;
        while (lo < hi) { int mid = (lo + hi) >> 1; if (batch[mid] < g + 1) lo = mid + 1; else hi = mid; }
        end = lo;
    }
    int len = end - start;
    int chunk = (len + NC - 1) / NC;
    int clo = start + c * chunk;
    int chi = min(clo + chunk, end);
    int tid = threadIdx.x;
    int d = tid & 127, half = tid >> 7;
    float s = 0.f, m = -INFINITY;
    for (int n = clo + half; n < chi; n += 2) {
        float v = bf2f(h16[(size_t)n * HH + d]);
        s += v; m = fmaxf(m, v);
    }
    __shared__ float ss[256], sm[256];
    ss[tid] = s; sm[tid] = m;
    __syncthreads();
    if (half == 0) {
        s += ss[tid + 128];
        m = fmaxf(m, sm[tid + 128]);
        psum[(size_t)blockIdx.x * HH + d] = s;
        pmax[(size_t)blockIdx.x * HH + d] = m;
    }
}

__global__ void pool2_kernel(const float* __restrict__ psum, const float* __restrict__ pmax,
                             const int* __restrict__ batch, float* __restrict__ out) {
    int g = blockIdx.x;
    int d = threadIdx.x;   // 128 threads
    int start, end;
    {
        int lo = 0, hi = NN;
        while (lo < hi) { int mid = (lo + hi) >> 1; if (batch[mid] < g) lo = mid + 1; else hi = mid; }
        start = lo;
        hi = NN;
        while (lo < hi) { int mid = (lo + hi) >> 1; if (batch[mid] < g + 1) lo = mid + 1; else hi = mid; }
        end = lo;
    }
    float s = 0.f, m = -INFINITY;
    #pragma unroll
    for (int c = 0; c < NC; ++c) {
        s += psum[(size_t)(g * NC + c) * HH + d];
        m = fmaxf(m, pmax[(size_t)(g * NC + c) * HH + d]);
    }
    int cg = end - start;
    out[g * 2 * HH + d] = s / fmaxf((float)cg, 1.0f);
    out[g * 2 * HH + HH + d] = (cg > 0) ? m : 0.0f;
}

// ================================================================ launch
extern "C" void kernel_launch(void* const* d_in, const int* in_sizes, int n_in,
                              void* d_out, int out_size, void* d_ws, size_t ws_size,
                              hipStream_t stream) {
    const float* x     = (const float*)d_in[0];
    const int*   ast   = (const int*)d_in[1];
    const int*   batch = (const int*)d_in[2];
    const int*   ei    = (const int*)d_in[3];
    const float* emb   = (const float*)d_in[4];
    const float* W_in  = (const float*)d_in[5];
    const float* b_in  = (const float*)d_in[6];
    const float* W_l   = (const float*)d_in[7];
    const float* b_l   = (const float*)d_in[8];
    const float* W_r   = (const float*)d_in[9];
    const float* gamma = (const float*)d_in[10];
    const float* beta  = (const float*)d_in[11];
    float* out = (float*)d_out;

    const int M  = TT * NN;
    const int NB = (M + 1023) / 1024;

    char* p = (char*)d_ws;
    unsigned short* h16a = (unsigned short*)p;  p += (size_t)NN * HH * 2;   // 25.6 MB
    unsigned short* ob16 = (unsigned short*)p;  p += (size_t)NN * HH * 2;   // 25.6 MB
    unsigned short* Wt16 = (unsigned short*)p;  p += (size_t)LL * WLSZ * 2;
    unsigned short* Wp_in = (unsigned short*)p; p += (size_t)32768 * 2;     // 64 KB
    float* blsum = (float*)p;                   p += LL * HH * 4;
    float* psum = (float*)p;                    p += (size_t)BB * NC * HH * 4;
    float* pmax = (float*)p;                    p += (size_t)BB * NC * HH * 4;
    int* cnt    = (int*)p;                      p += (size_t)M * 4;
    int* offs   = (int*)p;                      p += (size_t)M * 4;
    int* cursor = (int*)p;                      p += (size_t)M * 4;
    int* csr    = (int*)p;                      p += (size_t)TT * EE * 4;
    int* bsums  = (int*)p;

    hipMemsetAsync(cnt, 0, (size_t)M * sizeof(int), stream);
    count_kernel<<<(TT * EE + 255) / 256, 256, 0, stream>>>(ei, cnt);
    scan1_kernel<<<NB, 256, 0, stream>>>(cnt, offs, bsums, M);
    scan2_kernel<<<1, 512, 0, stream>>>(bsums, NB);
    scan3_kernel<<<(M + 255) / 256, 256, 0, stream>>>(offs, bsums, cursor, M);
    fill_kernel<<<(TT * EE + 255) / 256, 256, 0, stream>>>(ei, cursor, csr);
    wprep_kernel<<<(LL * 4 * HH * HH + 255) / 256, 256, 0, stream>>>(W_l, W_r, b_l, W_in,
                                                                     Wt16, Wp_in, blsum);

    int conv_grid = (NN + 63) / 64;
    int ln_grid = (NN + 3) / 4;
    input_proj_kernel<<<conv_grid, 512, 0, stream>>>(x, ast, emb, Wp_in, b_in, h16a);
    // layer 0
    conv_kernel<<<conv_grid, 512, 0, stream>>>(h16a, Wt16, blsum, offs, cnt, csr, ob16);
    layernorm_kernel<<<ln_grid, 256, 0, stream>>>((const unsigned*)ob16, gamma, beta,
                                                  (unsigned*)h16a, NN);
    // layer 1
    conv_kernel<<<conv_grid, 512, 0, stream>>>(h16a, Wt16 + (size_t)WLSZ, blsum + HH,
                                               offs, cnt, csr, ob16);
    layernorm_kernel<<<ln_grid, 256, 0, stream>>>((const unsigned*)ob16, gamma + HH, beta + HH,
                                                  (unsigned*)h16a, NN);
    // two-stage pooling
    pool1_kernel<<<BB * NC, 256, 0, stream>>>(h16a, batch, psum, pmax);
    pool2_kernel<<<BB, HH, 0, stream>>>(psum, pmax, batch, out);
}

// Round 13
// 322.516 us; speedup vs baseline: 1.1529x; 1.1529x over previous
//
#include <hip/hip_runtime.h>
#include <hip/hip_bf16.h>
#include <math.h>

#define NN 100000   // nodes
#define EE 300000   // edges per type
#define TT 3        // edge types
#define LL 2        // layers
#define HH 128      // hidden
#define FF 5        // node feat
#define TE 64       // type embed
#define NT 200      // num ast types
#define BB 64       // graphs
#define NC 16       // pooling chunks per graph
#define CSRCAP 512  // per-type per-block LDS index cap (mean ~192)
#define WLSZ 131072 // per-layer fragment-packed weight size (shorts)
#define KIN 96      // padded K for input projection (69 -> 96)
#define IALD 104    // input-proj LDS row stride (shorts)

typedef short bf16x8 __attribute__((ext_vector_type(8)));
typedef float f32x4  __attribute__((ext_vector_type(4)));

__device__ __forceinline__ float bf2f(unsigned short u) {
    union { unsigned i; float f; } v; v.i = ((unsigned)u) << 16; return v.f;
}
__device__ __forceinline__ float bflo(unsigned u) {
    union { unsigned i; float f; } v; v.i = u << 16; return v.f;
}
__device__ __forceinline__ float bfhi(unsigned u) {
    union { unsigned i; float f; } v; v.i = u & 0xFFFF0000u; return v.f;
}
__device__ __forceinline__ unsigned short f2bf(float f) {
    union { float f; unsigned i; } v; v.f = f;
    unsigned b = v.i + (0x7FFFu + ((v.i >> 16) & 1u));   // RNE
    return (unsigned short)(b >> 16);
}
__device__ __forceinline__ unsigned pk2(float a, float b) {
    return (unsigned)f2bf(a) | ((unsigned)f2bf(b) << 16);
}
// split x ~= hi + lo (two bf16); hi+lo reproduces x to ~2^-16 rel
__device__ __forceinline__ void split_bf(float x, unsigned short& hi, unsigned short& lo) {
    hi = f2bf(x);
    lo = f2bf(x - bf2f(hi));
}

// ================================================================ CSR build (validated R2)
__global__ void count_kernel(const int* __restrict__ ei, int* __restrict__ cnt) {
    int i = blockIdx.x * blockDim.x + threadIdx.x;
    if (i >= TT * EE) return;
    int t = i / EE, e = i - t * EE;
    int dst = ei[(t * 2 + 1) * EE + e];
    atomicAdd(&cnt[t * NN + dst], 1);
}

__global__ __launch_bounds__(256) void scan1_kernel(const int* __restrict__ cnt,
                                                    int* __restrict__ offs,
                                                    int* __restrict__ bsums, int M) {
    int tid = threadIdx.x;
    int base = blockIdx.x * 1024 + tid * 4;
    int a0 = 0, a1 = 0, a2 = 0, a3 = 0;
    if (base + 3 < M) { int4 v = *(const int4*)&cnt[base]; a0 = v.x; a1 = v.y; a2 = v.z; a3 = v.w; }
    else {
        if (base + 0 < M) a0 = cnt[base + 0];
        if (base + 1 < M) a1 = cnt[base + 1];
        if (base + 2 < M) a2 = cnt[base + 2];
        if (base + 3 < M) a3 = cnt[base + 3];
    }
    int s = a0 + a1 + a2 + a3;
    int lane = tid & 63, wv = tid >> 6;
    int x = s;
    #pragma unroll
    for (int o = 1; o < 64; o <<= 1) { int y = __shfl_up(x, o); if (lane >= o) x += y; }
    __shared__ int wsum[4];
    if (lane == 63) wsum[wv] = x;
    __syncthreads();
    int add = 0;
    for (int w = 0; w < wv; ++w) add += wsum[w];
    int incl = x + add;
    int e0 = incl - s, e1 = e0 + a0, e2 = e1 + a1, e3 = e2 + a2;
    if (base + 0 < M) offs[base + 0] = e0;
    if (base + 1 < M) offs[base + 1] = e1;
    if (base + 2 < M) offs[base + 2] = e2;
    if (base + 3 < M) offs[base + 3] = e3;
    if (tid == 255) bsums[blockIdx.x] = incl;
}

__global__ __launch_bounds__(512) void scan2_kernel(int* __restrict__ bsums, int NB) {
    int tid = threadIdx.x;
    int s = (tid < NB) ? bsums[tid] : 0;
    int lane = tid & 63, wv = tid >> 6;
    int x = s;
    #pragma unroll
    for (int o = 1; o < 64; o <<= 1) { int y = __shfl_up(x, o); if (lane >= o) x += y; }
    __shared__ int wsum[8];
    if (lane == 63) wsum[wv] = x;
    __syncthreads();
    int add = 0;
    for (int w = 0; w < wv; ++w) add += wsum[w];
    if (tid < NB) bsums[tid] = x + add - s;
}

__global__ void scan3_kernel(int* __restrict__ offs, const int* __restrict__ bsums,
                             int* __restrict__ cursor, int M) {
    int i = blockIdx.x * 256 + threadIdx.x;
    if (i >= M) return;
    int v = offs[i] + bsums[i >> 10];
    offs[i] = v;
    cursor[i] = v;
}

__global__ void fill_kernel(const int* __restrict__ ei, int* __restrict__ cursor,
                            int* __restrict__ csr) {
    int i = blockIdx.x * blockDim.x + threadIdx.x;
    if (i >= TT * EE) return;
    int t = i / EE, e = i - t * EE;
    int src = ei[(t * 2 + 0) * EE + e];
    int dst = ei[(t * 2 + 1) * EE + e];
    int pos = atomicAdd(&cursor[t * NN + dst], 1);
    csr[pos] = src;
}

// ================================================================ weight prep (conv + input-proj merged, validated R12)
__global__ void wprep_kernel(const float* __restrict__ W_l, const float* __restrict__ W_r,
                             const float* __restrict__ b_l, const float* __restrict__ W_in,
                             unsigned short* __restrict__ Wt16, unsigned short* __restrict__ Wp,
                             float* __restrict__ blsum) {
    int i = blockIdx.x * 256 + threadIdx.x;
    if (i < LL * 4 * HH * HH) {
        int lm = i >> 14;          // l*4 + m
        int ck = i & 16383;
        int col = ck >> 7, k = ck & 127;
        int l = lm >> 2, m = lm & 3;
        float v;
        if (m == 0) {
            v = 0.f;
            for (int t = 0; t < TT; ++t)
                v += W_r[(((size_t)(l * TT + t)) << 14) + k * HH + col];
        } else {
            v = W_l[(((size_t)(l * TT + (m - 1))) << 14) + k * HH + col];
        }
        unsigned short hi, lo;
        split_bf(v, hi, lo);
        int cg = col >> 4, l15 = col & 15;
        int ks = k >> 5, lh = (k >> 3) & 3, j = k & 7;
        int lane = lh * 16 + l15;
        size_t base = (size_t)l * WLSZ;
        int Phi = (m * 2 + 0) * 4 + ks;
        int Plo = Phi + 4;
        Wt16[base + (size_t)Phi * 4096 + cg * 512 + lane * 8 + j] = hi;
        Wt16[base + (size_t)Plo * 4096 + cg * 512 + lane * 8 + j] = lo;
    }
    if (i < KIN * HH) {
        int col = i & 127, k = i >> 7;
        float v = (k < TE + FF) ? W_in[k * HH + col] : 0.f;
        unsigned short hi, lo;
        split_bf(v, hi, lo);
        int cg = col >> 4, l15 = col & 15;
        int ks = k >> 5, lh = (k >> 3) & 3, j = k & 7;
        int lane = lh * 16 + l15;
        Wp[(size_t)ks * 4096 + cg * 512 + lane * 8 + j]       = hi;
        Wp[(size_t)(4 + ks) * 4096 + cg * 512 + lane * 8 + j] = lo;
    }
    if (i < LL * HH) {
        int l = i >> 7, j = i & 127;
        float s = 0.f;
        for (int t = 0; t < TT; ++t) s += b_l[(l * TT + t) * HH + j];
        blsum[i] = s;
    }
}

// ================================================================ input projection (split-bf16 MFMA, validated R11)
__global__ __launch_bounds__(512) void input_proj_kernel(
    const float* __restrict__ x, const int* __restrict__ ast,
    const float* __restrict__ emb, const unsigned short* __restrict__ Wp,
    const float* __restrict__ b_in, unsigned short* __restrict__ h16)
{
    __shared__ unsigned short Ahi[64 * IALD];   // 13.3 KB
    __shared__ unsigned short Alo[64 * IALD];   // 13.3 KB

    int tid = threadIdx.x;
    int row0 = blockIdx.x * 64;
    int w = tid >> 6, l = tid & 63;
    int l15 = l & 15, koff = (l >> 4) * 8;

    // ---- stage A-tile: 8 threads x 12 cols per row (96 cols)
    {
        int r = tid >> 3, sub = tid & 7;
        int gr = row0 + r;
        float v[12];
        #pragma unroll
        for (int j = 0; j < 12; ++j) v[j] = 0.f;
        if (gr < NN) {
            int a = ast[gr];
            #pragma unroll
            for (int j = 0; j < 12; ++j) {
                int k = sub * 12 + j;
                if (k < TE) v[j] = emb[a * TE + k];
                else if (k < TE + FF) v[j] = x[gr * FF + (k - TE)];
            }
        }
        unsigned short hs[12], ls[12];
        #pragma unroll
        for (int j = 0; j < 12; ++j) split_bf(v[j], hs[j], ls[j]);
        unsigned uh[6], ul[6];
        #pragma unroll
        for (int q = 0; q < 6; ++q) {
            uh[q] = (unsigned)hs[2 * q] | ((unsigned)hs[2 * q + 1] << 16);
            ul[q] = (unsigned)ls[2 * q] | ((unsigned)ls[2 * q + 1] << 16);
        }
        int base = r * IALD + sub * 12;
        uint2 h0; h0.x = uh[0]; h0.y = uh[1];
        uint2 h1; h1.x = uh[2]; h1.y = uh[3];
        uint2 h2; h2.x = uh[4]; h2.y = uh[5];
        uint2 l0; l0.x = ul[0]; l0.y = ul[1];
        uint2 l1; l1.x = ul[2]; l1.y = ul[3];
        uint2 l2; l2.x = ul[4]; l2.y = ul[5];
        *(uint2*)&Ahi[base + 0] = h0;
        *(uint2*)&Ahi[base + 4] = h1;
        *(uint2*)&Ahi[base + 8] = h2;
        *(uint2*)&Alo[base + 0] = l0;
        *(uint2*)&Alo[base + 4] = l1;
        *(uint2*)&Alo[base + 8] = l2;
    }
    __syncthreads();

    // ---- MFMA: 3 k-steps, W fragments direct from L2-hot pack
    f32x4 acc[4] = {};
    #pragma unroll
    for (int ks = 0; ks < 3; ++ks) {
        bf16x8 wh = *(const bf16x8*)&Wp[(size_t)ks * 4096 + w * 512 + l * 8];
        bf16x8 wl = *(const bf16x8*)&Wp[(size_t)(4 + ks) * 4096 + w * 512 + l * 8];
        int k0 = ks * 32 + koff;
        #pragma unroll
        for (int rt = 0; rt < 4; ++rt) {
            bf16x8 ah = *(const bf16x8*)&Ahi[(rt * 16 + l15) * IALD + k0];
            bf16x8 al = *(const bf16x8*)&Alo[(rt * 16 + l15) * IALD + k0];
            acc[rt] = __builtin_amdgcn_mfma_f32_16x16x32_bf16(ah, wh, acc[rt], 0, 0, 0);
            acc[rt] = __builtin_amdgcn_mfma_f32_16x16x32_bf16(al, wh, acc[rt], 0, 0, 0);
            acc[rt] = __builtin_amdgcn_mfma_f32_16x16x32_bf16(ah, wl, acc[rt], 0, 0, 0);
        }
    }

    // ---- bias + bf16 store (m89 C/D layout, validated epilogue pattern)
    {
        int col = w * 16 + l15;
        float bv = b_in[col];
        int rbase = row0 + (l >> 4) * 4;
        #pragma unroll
        for (int rt = 0; rt < 4; ++rt) {
            #pragma unroll
            for (int i = 0; i < 4; ++i) {
                int grr = rbase + rt * 16 + i;
                if (grr < NN) h16[(size_t)grr * HH + col] = f2bf(acc[rt][i] + bv);
            }
        }
    }
}

// ================================================================ conv layer + fused LayerNorm
// R13: gather reverted to R11 scalar loop (R12 batching regressed). LN fused
// into epilogue: acc+bias dumped f32 to reused LDS, 8-thread/row shfl reduce,
// bf16 write of LN output directly (R2-validated pattern, current layout).
#define ALD 136   // padded LDS stride (shorts): 272 B -> 2-way bank aliasing (free)
#define LNLD 132  // f32 LN buffer row stride

__global__ __launch_bounds__(512) void conv_kernel(
    const unsigned short* __restrict__ h16,      // [N][128] bf16 (dense A + gather)
    const unsigned short* __restrict__ Wt_l,     // fragment-packed, per-layer base
    const float* __restrict__ blsum_l,
    const float* __restrict__ gamma, const float* __restrict__ beta,
    const int* __restrict__ offs, const int* __restrict__ cnt, const int* __restrict__ csr,
    unsigned short* __restrict__ hout16)
{
    __shared__ char smem[64 * LNLD * 4];         // 33.8 KB (Ln overlays Ahi+csr)
    unsigned short* Ahi = (unsigned short*)smem;             // 17.4 KB
    int* csr_lds = (int*)(smem + 64 * ALD * 2);              // 6 KB  [TT][CSRCAP]
    float* Ln = (float*)smem;                                // 33.8 KB (reused at end)
    __shared__ int base_lds[TT], len_lds[TT], flag_lds[TT];

    int tid = threadIdx.x;
    int row0 = blockIdx.x * 64;
    int nrow = min(64, NN - row0);
    int w = tid >> 6, l = tid & 63;
    int l15 = l & 15, koff = (l >> 4) * 8;

    // ---- stage CSR ranges (rows consecutive -> contiguous csr slice per type)
    if (tid < TT) {
        int t = tid;
        int last = row0 + nrow - 1;
        int b = offs[t * NN + row0];
        int e = offs[t * NN + last] + cnt[t * NN + last];
        base_lds[t] = b;
        len_lds[t] = e - b;
        flag_lds[t] = (e - b) <= CSRCAP;
    }
    __syncthreads();
    #pragma unroll
    for (int t = 0; t < TT; ++t) {
        if (flag_lds[t]) {
            int b = base_lds[t], len = len_lds[t];
            for (int i = tid; i < len; i += 512) csr_lds[t * CSRCAP + i] = csr[b + i];
        }
    }
    __syncthreads();

    int r = tid >> 3, sub = tid & 7;
    int gr = row0 + r;

    f32x4 acc[4] = {};

    #pragma unroll
    for (int m = 0; m < 4; ++m) {
        // ---- stage A-tile (single bf16 plane)
        if (m == 0) {
            #pragma unroll
            for (int s2 = 0; s2 < 2; ++s2) {
                int c16 = s2 * 512 + tid;
                int rr = c16 >> 4, k0 = (c16 & 15) * 8;
                int grr = row0 + rr;
                uint4 hv = {0u, 0u, 0u, 0u};
                if (grr < NN) hv = *(const uint4*)&h16[(size_t)grr * 128 + k0];
                *(uint4*)&Ahi[rr * ALD + k0] = hv;
            }
        } else {
            int t = m - 1;   // static under #pragma unroll
            // ---- gather mean_t from bf16 h (32B/edge/thread), f32 sums -> bf16 (R11 verbatim)
            float ms[16];
            #pragma unroll
            for (int j = 0; j < 16; ++j) ms[j] = 0.f;
            float inv = 0.f;
            if (gr < NN) {
                int o = offs[t * NN + gr];
                int c = cnt[t * NN + gr];
                inv = (c > 0) ? 1.0f / (float)c : 0.0f;
                bool inl = flag_lds[t] != 0;
                int rel = o - base_lds[t];
                const unsigned* h16u = (const unsigned*)h16;
                for (int j = 0; j < c; ++j) {
                    int src = inl ? csr_lds[t * CSRCAP + rel + j] : csr[o + j];
                    const uint4* hp = (const uint4*)&h16u[(size_t)src * 64 + sub * 8];
                    uint4 v0 = hp[0], v1 = hp[1];
                    ms[0]  += bflo(v0.x); ms[1]  += bfhi(v0.x);
                    ms[2]  += bflo(v0.y); ms[3]  += bfhi(v0.y);
                    ms[4]  += bflo(v0.z); ms[5]  += bfhi(v0.z);
                    ms[6]  += bflo(v0.w); ms[7]  += bfhi(v0.w);
                    ms[8]  += bflo(v1.x); ms[9]  += bfhi(v1.x);
                    ms[10] += bflo(v1.y); ms[11] += bfhi(v1.y);
                    ms[12] += bflo(v1.z); ms[13] += bfhi(v1.z);
                    ms[14] += bflo(v1.w); ms[15] += bfhi(v1.w);
                }
            }
            uint4 hv0, hv1;
            hv0.x = pk2(ms[0] * inv,  ms[1] * inv);
            hv0.y = pk2(ms[2] * inv,  ms[3] * inv);
            hv0.z = pk2(ms[4] * inv,  ms[5] * inv);
            hv0.w = pk2(ms[6] * inv,  ms[7] * inv);
            hv1.x = pk2(ms[8] * inv,  ms[9] * inv);
            hv1.y = pk2(ms[10] * inv, ms[11] * inv);
            hv1.z = pk2(ms[12] * inv, ms[13] * inv);
            hv1.w = pk2(ms[14] * inv, ms[15] * inv);
            *(uint4*)&Ahi[r * ALD + sub * 16]     = hv0;
            *(uint4*)&Ahi[r * ALD + sub * 16 + 8] = hv1;
        }
        __syncthreads();
        // ---- MFMA: A single-plane x W split (wh + wl), W direct from L2-hot pack
        #pragma unroll
        for (int ks = 0; ks < 4; ++ks) {
            bf16x8 wh = *(const bf16x8*)&Wt_l[(size_t)(8 * m + ks) * 4096 + w * 512 + l * 8];
            bf16x8 wl = *(const bf16x8*)&Wt_l[(size_t)(8 * m + 4 + ks) * 4096 + w * 512 + l * 8];
            int k0 = ks * 32 + koff;
            #pragma unroll
            for (int rt = 0; rt < 4; ++rt) {
                bf16x8 ah = *(const bf16x8*)&Ahi[(rt * 16 + l15) * ALD + k0];
                acc[rt] = __builtin_amdgcn_mfma_f32_16x16x32_bf16(ah, wh, acc[rt], 0, 0, 0);
                acc[rt] = __builtin_amdgcn_mfma_f32_16x16x32_bf16(ah, wl, acc[rt], 0, 0, 0);
            }
        }
        __syncthreads();   // before next m overwrites A (also frees LDS for Ln)
    }

    // ---- dump acc+bias to f32 LDS [64][132] (m89 C/D layout: col=w*16+l15, row=(l>>4)*4+i+rt*16)
    {
        int col = w * 16 + l15;
        float bv = blsum_l[col];
        int rloc = (l >> 4) * 4;
        #pragma unroll
        for (int rt = 0; rt < 4; ++rt) {
            #pragma unroll
            for (int i = 0; i < 4; ++i) {
                Ln[(rloc + rt * 16 + i) * LNLD + col] = acc[rt][i] + bv;
            }
        }
    }
    __syncthreads();
    // ---- fused LayerNorm: 8 threads/row, shfl_xor reduce, bf16 write
    {
        const float* Lr = Ln + r * LNLD + sub * 16;
        float4 v0 = *(const float4*)(Lr + 0);
        float4 v1 = *(const float4*)(Lr + 4);
        float4 v2 = *(const float4*)(Lr + 8);
        float4 v3 = *(const float4*)(Lr + 12);
        float s = v0.x + v0.y + v0.z + v0.w + v1.x + v1.y + v1.z + v1.w
                + v2.x + v2.y + v2.z + v2.w + v3.x + v3.y + v3.z + v3.w;
        float q = v0.x*v0.x + v0.y*v0.y + v0.z*v0.z + v0.w*v0.w
                + v1.x*v1.x + v1.y*v1.y + v1.z*v1.z + v1.w*v1.w
                + v2.x*v2.x + v2.y*v2.y + v2.z*v2.z + v2.w*v2.w
                + v3.x*v3.x + v3.y*v3.y + v3.z*v3.z + v3.w*v3.w;
        #pragma unroll
        for (int o = 1; o < 8; o <<= 1) { s += __shfl_xor(s, o); q += __shfl_xor(q, o); }
        float mu = s * (1.0f / HH);
        float var = q * (1.0f / HH) - mu * mu;
        float rs = rsqrtf(var + 1e-5f);
        if (gr < NN) {
            const float4* g4 = (const float4*)(gamma + sub * 16);
            const float4* b4 = (const float4*)(beta + sub * 16);
            float4 g0 = g4[0], g1 = g4[1], g2 = g4[2], g3 = g4[3];
            float4 e0 = b4[0], e1 = b4[1], e2 = b4[2], e3 = b4[3];
            uint4 o0, o1;
            o0.x = pk2((v0.x - mu) * rs * g0.x + e0.x, (v0.y - mu) * rs * g0.y + e0.y);
            o0.y = pk2((v0.z - mu) * rs * g0.z + e0.z, (v0.w - mu) * rs * g0.w + e0.w);
            o0.z = pk2((v1.x - mu) * rs * g1.x + e1.x, (v1.y - mu) * rs * g1.y + e1.y);
            o0.w = pk2((v1.z - mu) * rs * g1.z + e1.z, (v1.w - mu) * rs * g1.w + e1.w);
            o1.x = pk2((v2.x - mu) * rs * g2.x + e2.x, (v2.y - mu) * rs * g2.y + e2.y);
            o1.y = pk2((v2.z - mu) * rs * g2.z + e2.z, (v2.w - mu) * rs * g2.w + e2.w);
            o1.z = pk2((v3.x - mu) * rs * g3.x + e3.x, (v3.y - mu) * rs * g3.y + e3.y);
            o1.w = pk2((v3.z - mu) * rs * g3.z + e3.z, (v3.w - mu) * rs * g3.w + e3.w);
            uint4* op = (uint4*)&hout16[(size_t)gr * 128 + sub * 16];
            op[0] = o0; op[1] = o1;
        }
    }
}

// ================================================================ two-stage pooling (validated R10)
__global__ void pool1_kernel(const unsigned short* __restrict__ h16,
                             const int* __restrict__ batch,
                             float* __restrict__ psum, float* __restrict__ pmax) {
    int g = blockIdx.x >> 4, c = blockIdx.x & (NC - 1);
    int start, end;
    {
        int lo = 0, hi = NN;
        while (lo < hi) { int mid = (lo + hi) >> 1; if (batch[mid] < g) lo = mid + 1; else hi = mid; }
        start = lo;
        hi = NN;
        while (lo < hi) { int mid = (lo + hi) >> 1; if (batch[mid] < g + 1) lo = mid + 1; else hi = mid; }
        end = lo;
    }
    int len = end - start;
    int chunk = (len + NC - 1) / NC;
    int clo = start + c * chunk;
    int chi = min(clo + chunk, end);
    int tid = threadIdx.x;
    int d = tid & 127, half = tid >> 7;
    float s = 0.f, m = -INFINITY;
    for (int n = clo + half; n < chi; n += 2) {
        float v = bf2f(h16[(size_t)n * HH + d]);
        s += v; m = fmaxf(m, v);
    }
    __shared__ float ss[256], sm[256];
    ss[tid] = s; sm[tid] = m;
    __syncthreads();
    if (half == 0) {
        s += ss[tid + 128];
        m = fmaxf(m, sm[tid + 128]);
        psum[(size_t)blockIdx.x * HH + d] = s;
        pmax[(size_t)blockIdx.x * HH + d] = m;
    }
}

__global__ void pool2_kernel(const float* __restrict__ psum, const float* __restrict__ pmax,
                             const int* __restrict__ batch, float* __restrict__ out) {
    int g = blockIdx.x;
    int d = threadIdx.x;   // 128 threads
    int start, end;
    {
        int lo = 0, hi = NN;
        while (lo < hi) { int mid = (lo + hi) >> 1; if (batch[mid] < g) lo = mid + 1; else hi = mid; }
        start = lo;
        hi = NN;
        while (lo < hi) { int mid = (lo + hi) >> 1; if (batch[mid] < g + 1) lo = mid + 1; else hi = mid; }
        end = lo;
    }
    float s = 0.f, m = -INFINITY;
    #pragma unroll
    for (int c = 0; c < NC; ++c) {
        s += psum[(size_t)(g * NC + c) * HH + d];
        m = fmaxf(m, pmax[(size_t)(g * NC + c) * HH + d]);
    }
    int cg = end - start;
    out[g * 2 * HH + d] = s / fmaxf((float)cg, 1.0f);
    out[g * 2 * HH + HH + d] = (cg > 0) ? m : 0.0f;
}

// ================================================================ launch
extern "C" void kernel_launch(void* const* d_in, const int* in_sizes, int n_in,
                              void* d_out, int out_size, void* d_ws, size_t ws_size,
                              hipStream_t stream) {
    const float* x     = (const float*)d_in[0];
    const int*   ast   = (const int*)d_in[1];
    const int*   batch = (const int*)d_in[2];
    const int*   ei    = (const int*)d_in[3];
    const float* emb   = (const float*)d_in[4];
    const float* W_in  = (const float*)d_in[5];
    const float* b_in  = (const float*)d_in[6];
    const float* W_l   = (const float*)d_in[7];
    const float* b_l   = (const float*)d_in[8];
    const float* W_r   = (const float*)d_in[9];
    const float* gamma = (const float*)d_in[10];
    const float* beta  = (const float*)d_in[11];
    float* out = (float*)d_out;

    const int M  = TT * NN;
    const int NB = (M + 1023) / 1024;

    char* p = (char*)d_ws;
    unsigned short* h16a = (unsigned short*)p;  p += (size_t)NN * HH * 2;   // 25.6 MB
    unsigned short* h16b = (unsigned short*)p;  p += (size_t)NN * HH * 2;   // 25.6 MB
    unsigned short* Wt16 = (unsigned short*)p;  p += (size_t)LL * WLSZ * 2;
    unsigned short* Wp_in = (unsigned short*)p; p += (size_t)32768 * 2;     // 64 KB
    float* blsum = (float*)p;                   p += LL * HH * 4;
    float* psum = (float*)p;                    p += (size_t)BB * NC * HH * 4;
    float* pmax = (float*)p;                    p += (size_t)BB * NC * HH * 4;
    int* cnt    = (int*)p;                      p += (size_t)M * 4;
    int* offs   = (int*)p;                      p += (size_t)M * 4;
    int* cursor = (int*)p;                      p += (size_t)M * 4;
    int* csr    = (int*)p;                      p += (size_t)TT * EE * 4;
    int* bsums  = (int*)p;

    hipMemsetAsync(cnt, 0, (size_t)M * sizeof(int), stream);
    count_kernel<<<(TT * EE + 255) / 256, 256, 0, stream>>>(ei, cnt);
    scan1_kernel<<<NB, 256, 0, stream>>>(cnt, offs, bsums, M);
    scan2_kernel<<<1, 512, 0, stream>>>(bsums, NB);
    scan3_kernel<<<(M + 255) / 256, 256, 0, stream>>>(offs, bsums, cursor, M);
    fill_kernel<<<(TT * EE + 255) / 256, 256, 0, stream>>>(ei, cursor, csr);
    wprep_kernel<<<(LL * 4 * HH * HH + 255) / 256, 256, 0, stream>>>(W_l, W_r, b_l, W_in,
                                                                     Wt16, Wp_in, blsum);

    int conv_grid = (NN + 63) / 64;
    input_proj_kernel<<<conv_grid, 512, 0, stream>>>(x, ast, emb, Wp_in, b_in, h16a);
    // layer 0: h16a -> h16b (conv + fused LN)
    conv_kernel<<<conv_grid, 512, 0, stream>>>(h16a, Wt16, blsum, gamma, beta,
                                               offs, cnt, csr, h16b);
    // layer 1: h16b -> h16a (conv + fused LN)
    conv_kernel<<<conv_grid, 512, 0, stream>>>(h16b, Wt16 + (size_t)WLSZ, blsum + HH,
                                               gamma + HH, beta + HH,
                                               offs, cnt, csr, h16a);
    // two-stage pooling
    pool1_kernel<<<BB * NC, 256, 0, stream>>>(h16a, batch, psum, pmax);
    pool2_kernel<<<BB, HH, 0, stream>>>(psum, pmax, batch, out);
}